// Round 5
// baseline (766.279 us; speedup 1.0000x reference)
//
#include <hip/hip_runtime.h>
#include <math.h>

#define BATCH 4096
#define HDIM  1024
#define KDIM0 7150
#define KP0   7168
#define KT0   224          // KP0/32
#define KTH   32           // HDIM/32
#define NACT  47
#define NA2   94
#define NEGC  -1000000000.0f

// output layout (floats): logits [0,385024), logp [385024,393216),
// actions [393216,401408), value [401408,405504)
#define LP_OFF  385024
#define ACT_OFF 393216
#define VAL_OFF 401408

typedef _Float16 half8_t  __attribute__((ext_vector_type(8)));
typedef _Float16 half4_t  __attribute__((ext_vector_type(4)));
typedef float    float4_t __attribute__((ext_vector_type(4)));

#define GLOAD16(gp, lp) __builtin_amdgcn_global_load_lds( \
    (__attribute__((address_space(1))) void*)(gp), \
    (__attribute__((address_space(3))) void*)(lp), 16, 0, 0)

// Fragment-tile order for a [R][Kp] f16 plane (R = rows of A / cols of W^T):
//   tile = rt*KT + kt ; within tile: lane = quad*16 + (r%16), quad=(k%32)/8,
//   halfs addr = tile*512 + lane*8 + (k%8).  (mfma_f32_16x16x32_f16 layout)

// ---------------------------------------------------------------------------
// Weight convert body: W[K][HDIM] fp32 -> hi/lo f16 planes of W^T, frag order.
// ---------------------------------------------------------------------------
__device__ __forceinline__ void wconv_body(
    const float* __restrict__ W, _Float16* __restrict__ Wh,
    _Float16* __restrict__ Wl, int K, int KT, int bxk, int byn)
{
  __shared__ float T[64][65];
  const int k0 = bxk * 64, n0 = byn * 64, t = threadIdx.x;
#pragma unroll
  for (int p = 0; p < 16; ++p) {
    const int idx = p * 256 + t;
    const int r = idx >> 6, c = idx & 63;
    T[r][c] = (k0 + r < K) ? W[(size_t)(k0 + r) * HDIM + n0 + c] : 0.f;
  }
  __syncthreads();
#pragma unroll
  for (int ss = 0; ss < 2; ++ss) {
    const int s    = ss * 256 + t;
    const int tile = s >> 6;            // 0..7 = 2 kt x 4 nt
    const int ktl  = tile >> 2, ntl = tile & 3;
    const int lane = s & 63;
    const int quad = lane >> 4, nr = lane & 15;
    half8_t h, l;
#pragma unroll
    for (int j = 0; j < 8; ++j) {
      const float v = T[ktl * 32 + quad * 8 + j][ntl * 16 + nr];
      const _Float16 hh = (_Float16)v;
      h[j] = hh;
      l[j] = (_Float16)((v - (float)hh) * 4096.f);
    }
    const size_t o = ((size_t)((n0 / 16 + ntl) * KT + (k0 / 32 + ktl)) * 64 + lane) * 8;
    *(half8_t*)(Wh + o) = h;
    *(half8_t*)(Wl + o) = l;
  }
}

// ---------------------------------------------------------------------------
// Merged prep: one launch does wconv(W0) + wconv(W1) + wconv(W2) + pack_wcat.
// Block-range dispatch: [0,1792) W0, [1792,2048) W1, [2048,2304) W2,
// [2304,2688) pack.
// ---------------------------------------------------------------------------
__global__ __launch_bounds__(256) void prep_kernel(
    const float* __restrict__ W0, _Float16* __restrict__ w0h, _Float16* __restrict__ w0l,
    const float* __restrict__ W1, _Float16* __restrict__ w1h, _Float16* __restrict__ w1l,
    const float* __restrict__ W2, _Float16* __restrict__ w2h, _Float16* __restrict__ w2l,
    const float* __restrict__ Wp, const float* __restrict__ Wv,
    float* __restrict__ Wc)
{
  int id = blockIdx.x;
  if (id < 1792) {                       // W0: 112 k-chunks x 16 n-chunks
    wconv_body(W0, w0h, w0l, KDIM0, KT0, id % 112, id / 112);
    return;
  }
  id -= 1792;
  if (id < 256) {                        // W1: 16 x 16
    wconv_body(W1, w1h, w1l, HDIM, KTH, id % 16, id / 16);
    return;
  }
  id -= 256;
  if (id < 256) {                        // W2: 16 x 16
    wconv_body(W2, w2h, w2l, HDIM, KTH, id % 16, id / 16);
    return;
  }
  id -= 256;                             // pack Wcat[1024][96]
  const int i = id * 256 + threadIdx.x;
  const int k = i / 96, c = i % 96;
  float v = 0.f;
  if (c < 94)       v = Wp[(size_t)k * 94 + c];
  else if (c == 94) v = Wv[k];
  Wc[i] = v;
}

// ---------------------------------------------------------------------------
// f16x3 split GEMM for layer 0, A read DIRECTLY from fp32 obs (adecomp fused).
// Tile 64m x 128n, 8 waves (2m x 4n), wave tile 32x32. LDS 48KB -> 3
// blocks/CU (24 waves). Waves 0-3 stage+convert the 4 A m-tiles (+ their W
// n-tile); waves 4-7 stage W only. 2-phase double-buffered: stage tile t+1
// before MFMA on tile t, one __syncthreads per k-tile; A regs 2-deep.
// ---------------------------------------------------------------------------
__global__ __launch_bounds__(512, 6) void gemm_obs_kernel(
    const float* __restrict__ A,
    const _Float16* __restrict__ Wh, const _Float16* __restrict__ Wl,
    float* __restrict__ C, int ktsplit)
{
  __shared__ _Float16 As[2][2][4][512];   // 16KB [buf][plane][mt][frag]
  __shared__ _Float16 Ws[2][2][8][512];   // 32KB [buf][plane][nt][frag]
  // XCD-aware bijective swizzle: 1024 blocks, 8 XCDs, chunk=128
  const int f  = blockIdx.x + 8 * (blockIdx.y + 64 * blockIdx.z);
  const int nf = (f & 7) * 128 + (f >> 3);
  const int bx = nf & 7, by = (nf >> 3) & 63, bz = nf >> 9;

  const int t    = threadIdx.x;
  const int lane = t & 63;
  const int w    = t >> 6;
  const int nt0  = bx * 8;
  const int mt0  = by * 4;
  const int ktb  = bz * ktsplit;
  const int nit  = ktsplit;            // 112 k-tiles per z-half, even
  const int l15  = lane & 15, quad = lane >> 4;
  const int wmi  = (w >> 2) * 2;       // {0,2}
  const int wni  = (w & 3) * 2;        // {0,2,4,6}
  const bool aw  = (w < 4);            // A-staging waves

  // wave w<4 stages A m-tile mt0+w (fp32); every wave stages W n-tile nt0+w
  const float* aRow = A + (size_t)((mt0 + (w & 3)) * 16 + l15) * KDIM0 + quad * 8;
  const _Float16* wS0 = Wh + (size_t)(nt0 + w) * KT0 * 512 + lane * 8;
  const _Float16* wS1 = Wl + (size_t)(nt0 + w) * KT0 * 512 + lane * 8;

  struct AF8 { float v[8]; };
  auto loadA = [&](int kt) {
    AF8 r;
    const int kg = kt * 32 + quad * 8;
    const float* src = aRow + (size_t)kt * 32;
    if (kg + 8 <= KDIM0) {
#pragma unroll
      for (int c = 0; c < 4; ++c) {       // 8B-aligned only (KDIM0 odd stride)
        const float2 p = *(const float2*)(src + c * 2);
        r.v[c * 2] = p.x; r.v[c * 2 + 1] = p.y;
      }
    } else {
#pragma unroll
      for (int j = 0; j < 8; ++j)
        r.v[j] = (kg + j < KDIM0) ? src[j] : 0.f;
    }
    return r;
  };
  auto gw = [&](int kt, int buf) {
    GLOAD16(wS0 + (size_t)kt * 512, &Ws[buf][0][w][0]);
    GLOAD16(wS1 + (size_t)kt * 512, &Ws[buf][1][w][0]);
  };
  auto convst = [&](const AF8& a, int buf) {
    half8_t h, l;
#pragma unroll
    for (int j = 0; j < 8; ++j) {
      const float v = a.v[j];
      const _Float16 hh = (_Float16)v;
      h[j] = hh;
      l[j] = (_Float16)((v - (float)hh) * 4096.f);
    }
    *(half8_t*)&As[buf][0][w & 3][lane * 8] = h;
    *(half8_t*)&As[buf][1][w & 3][lane * 8] = l;
  };

  float4_t acc[2][2], accx[2][2];
#pragma unroll
  for (int i = 0; i < 2; ++i)
#pragma unroll
    for (int j = 0; j < 2; ++j) {
      acc[i][j]  = (float4_t){0.f, 0.f, 0.f, 0.f};
      accx[i][j] = (float4_t){0.f, 0.f, 0.f, 0.f};
    }

  auto mm = [&](int buf) {
    half8_t ah[2], al[2], wh[2], wl[2];
#pragma unroll
    for (int i = 0; i < 2; ++i) {
      ah[i] = *(const half8_t*)&As[buf][0][wmi + i][lane * 8];
      al[i] = *(const half8_t*)&As[buf][1][wmi + i][lane * 8];
    }
#pragma unroll
    for (int j = 0; j < 2; ++j) {
      wh[j] = *(const half8_t*)&Ws[buf][0][wni + j][lane * 8];
      wl[j] = *(const half8_t*)&Ws[buf][1][wni + j][lane * 8];
    }
#pragma unroll
    for (int i = 0; i < 2; ++i)
#pragma unroll
      for (int j = 0; j < 2; ++j) {
        acc[i][j]  = __builtin_amdgcn_mfma_f32_16x16x32_f16(ah[i], wh[j], acc[i][j], 0, 0, 0);
        accx[i][j] = __builtin_amdgcn_mfma_f32_16x16x32_f16(ah[i], wl[j], accx[i][j], 0, 0, 0);
        accx[i][j] = __builtin_amdgcn_mfma_f32_16x16x32_f16(al[i], wh[j], accx[i][j], 0, 0, 0);
      }
  };

  // prologue: tile0 staged into buf0; A regs for tiles 0,1 in flight
  AF8 vaE, vaO;
  if (aw) { vaE = loadA(ktb + 0); vaO = loadA(ktb + 1); }
  gw(ktb + 0, 0);
  if (aw) convst(vaE, 0);
  __syncthreads();

  for (int it = 0; it < nit; it += 2) {
    // even tile (buf0): stage tile it+1 -> buf1, prefetch A it+2
    gw(ktb + it + 1, 1);
    if (aw) {
      if (it + 2 < nit) vaE = loadA(ktb + it + 2);
      convst(vaO, 1);
    }
    mm(0);
    __syncthreads();
    // odd tile (buf1): stage tile it+2 -> buf0, prefetch A it+3
    if (it + 2 < nit) gw(ktb + it + 2, 0);
    if (aw) {
      if (it + 3 < nit) vaO = loadA(ktb + it + 3);
      if (it + 2 < nit) convst(vaE, 0);
    }
    mm(1);
    __syncthreads();
  }

  float* Cb = C + (size_t)bz * ((size_t)BATCH * HDIM);
  const float sc = 1.0f / 4096.0f;
#pragma unroll
  for (int i = 0; i < 2; ++i) {
    const int row0 = (mt0 + wmi + i) * 16 + quad * 4;
#pragma unroll
    for (int j = 0; j < 2; ++j) {
      const int col = (nt0 + wni + j) * 16 + l15;
      float* cp = Cb + (size_t)row0 * HDIM + col;
#pragma unroll
      for (int r = 0; r < 4; ++r)
        cp[(size_t)r * HDIM] = acc[i][j][r] + accx[i][j][r] * sc;
    }
  }
}

// ---------------------------------------------------------------------------
// f16x3 split GEMM (layers 1/2). Tile 64m x 128n, 48KB LDS -> 3 blocks/CU.
// Waves 0-3 stage A m-tiles (2 gload_lds), all waves stage their W n-tile.
// 2-phase double-buffered, one __syncthreads per k-tile. XCD-swizzled grid.
// ---------------------------------------------------------------------------
__global__ __launch_bounds__(512, 6) void gemm_frag2_kernel(
    const _Float16* __restrict__ Ah, const _Float16* __restrict__ Al,
    const _Float16* __restrict__ Wh, const _Float16* __restrict__ Wl,
    float* __restrict__ C, int KT, int ktsplit)
{
  __shared__ _Float16 As[2][2][4][512];   // 16KB
  __shared__ _Float16 Ws[2][2][8][512];   // 32KB
  const int f  = blockIdx.x + 8 * (blockIdx.y + 64 * blockIdx.z);
  const int nf = (f & 7) * 128 + (f >> 3);
  const int bx = nf & 7, by = (nf >> 3) & 63, bz = nf >> 9;

  const int t    = threadIdx.x;
  const int lane = t & 63;
  const int w    = t >> 6;
  const int nt0  = bx * 8;
  const int mt0  = by * 4;
  const int ktb  = bz * ktsplit;
  const int nit  = ktsplit;            // 16 k-tiles per z-half, even
  const int l15  = lane & 15, quad = lane >> 4;
  const int wmi  = (w >> 2) * 2;
  const int wni  = (w & 3) * 2;
  const bool aw  = (w < 4);

  const _Float16* aS0 = Ah + (size_t)(mt0 + (w & 3)) * KT * 512 + lane * 8;
  const _Float16* aS1 = Al + (size_t)(mt0 + (w & 3)) * KT * 512 + lane * 8;
  const _Float16* wS0 = Wh + (size_t)(nt0 + w) * KT * 512 + lane * 8;
  const _Float16* wS1 = Wl + (size_t)(nt0 + w) * KT * 512 + lane * 8;

  auto st = [&](int kt, int buf) {
    if (aw) {
      GLOAD16(aS0 + (size_t)kt * 512, &As[buf][0][w & 3][0]);
      GLOAD16(aS1 + (size_t)kt * 512, &As[buf][1][w & 3][0]);
    }
    GLOAD16(wS0 + (size_t)kt * 512, &Ws[buf][0][w][0]);
    GLOAD16(wS1 + (size_t)kt * 512, &Ws[buf][1][w][0]);
  };

  float4_t acc[2][2], accx[2][2];
#pragma unroll
  for (int i = 0; i < 2; ++i)
#pragma unroll
    for (int j = 0; j < 2; ++j) {
      acc[i][j]  = (float4_t){0.f, 0.f, 0.f, 0.f};
      accx[i][j] = (float4_t){0.f, 0.f, 0.f, 0.f};
    }

  auto mm = [&](int buf) {
    half8_t ah[2], al[2], wh[2], wl[2];
#pragma unroll
    for (int i = 0; i < 2; ++i) {
      ah[i] = *(const half8_t*)&As[buf][0][wmi + i][lane * 8];
      al[i] = *(const half8_t*)&As[buf][1][wmi + i][lane * 8];
    }
#pragma unroll
    for (int j = 0; j < 2; ++j) {
      wh[j] = *(const half8_t*)&Ws[buf][0][wni + j][lane * 8];
      wl[j] = *(const half8_t*)&Ws[buf][1][wni + j][lane * 8];
    }
#pragma unroll
    for (int i = 0; i < 2; ++i)
#pragma unroll
      for (int j = 0; j < 2; ++j) {
        acc[i][j]  = __builtin_amdgcn_mfma_f32_16x16x32_f16(ah[i], wh[j], acc[i][j], 0, 0, 0);
        accx[i][j] = __builtin_amdgcn_mfma_f32_16x16x32_f16(ah[i], wl[j], accx[i][j], 0, 0, 0);
        accx[i][j] = __builtin_amdgcn_mfma_f32_16x16x32_f16(al[i], wh[j], accx[i][j], 0, 0, 0);
      }
  };

  st(ktb, 0);
  __syncthreads();
  for (int it = 0; it < nit; it += 2) {
    st(ktb + it + 1, 1);
    mm(0);
    __syncthreads();
    if (it + 2 < nit) st(ktb + it + 2, 0);
    mm(1);
    __syncthreads();
  }

  float* Cb = C + (size_t)bz * ((size_t)BATCH * HDIM);
  const float sc = 1.0f / 4096.0f;
#pragma unroll
  for (int i = 0; i < 2; ++i) {
    const int row0 = (mt0 + wmi + i) * 16 + quad * 4;
#pragma unroll
    for (int j = 0; j < 2; ++j) {
      const int col = (nt0 + wni + j) * 16 + l15;
      float* cp = Cb + (size_t)row0 * HDIM + col;
#pragma unroll
      for (int r = 0; r < 4; ++r)
        cp[(size_t)r * HDIM] = acc[i][j][r] + accx[i][j][r] * sc;
    }
  }
}

// ---------------------------------------------------------------------------
// sum halves + bias + LayerNorm + ReLU -> hi/lo f16 planes (fragment order).
// 1024 thr = 16 waves; wave w = row mt*16+w, wave-local reductions.
// ---------------------------------------------------------------------------
__global__ __launch_bounds__(1024) void ln_relu_f16_frag_kernel(
    const float* __restrict__ x0, const float* __restrict__ x1,
    const float* __restrict__ bias,
    const float* __restrict__ g, const float* __restrict__ be,
    _Float16* __restrict__ oh, _Float16* __restrict__ ol)
{
  const int t = threadIdx.x;
  const int w = t >> 6, lane = t & 63;
  const int mt = blockIdx.x;
  const float* xr0 = x0 + (size_t)(mt * 16 + w) * HDIM;
  const float* xr1 = x1 + (size_t)(mt * 16 + w) * HDIM;

  float4 v[4];
  float s = 0.f;
#pragma unroll
  for (int c = 0; c < 4; ++c) {
    const int k = c * 256 + lane * 4;
    const float4 a = *(const float4*)(xr0 + k);
    const float4 b = *(const float4*)(xr1 + k);
    const float4 bb = *(const float4*)(bias + k);
    v[c].x = a.x + b.x + bb.x; v[c].y = a.y + b.y + bb.y;
    v[c].z = a.z + b.z + bb.z; v[c].w = a.w + b.w + bb.w;
    s += (v[c].x + v[c].y) + (v[c].z + v[c].w);
  }
#pragma unroll
  for (int o = 32; o; o >>= 1) s += __shfl_xor(s, o, 64);
  const float mean = s * (1.0f / HDIM);

  float s2 = 0.f;
#pragma unroll
  for (int c = 0; c < 4; ++c) {
    v[c].x -= mean; v[c].y -= mean; v[c].z -= mean; v[c].w -= mean;
    s2 += (v[c].x * v[c].x + v[c].y * v[c].y) + (v[c].z * v[c].z + v[c].w * v[c].w);
  }
#pragma unroll
  for (int o = 32; o; o >>= 1) s2 += __shfl_xor(s2, o, 64);
  const float inv = 1.0f / sqrtf(s2 * (1.0f / HDIM) + 1e-5f);

  const int kt_b  = lane >> 3;
  const int quad  = (lane >> 1) & 3;
  const int jb    = (lane & 1) * 4;
#pragma unroll
  for (int c = 0; c < 4; ++c) {
    const int k = c * 256 + lane * 4;
    const float4 gg = *(const float4*)(g + k);
    const float4 ee = *(const float4*)(be + k);
    float r0 = fmaxf(fmaf(v[c].x * inv, gg.x, ee.x), 0.f);
    float r1 = fmaxf(fmaf(v[c].y * inv, gg.y, ee.y), 0.f);
    float r2 = fmaxf(fmaf(v[c].z * inv, gg.z, ee.z), 0.f);
    float r3 = fmaxf(fmaf(v[c].w * inv, gg.w, ee.w), 0.f);
    const _Float16 h0 = (_Float16)r0, h1 = (_Float16)r1, h2 = (_Float16)r2, h3 = (_Float16)r3;
    const half4_t hv = {h0, h1, h2, h3};
    const half4_t lv = {(_Float16)((r0 - (float)h0) * 4096.f),
                        (_Float16)((r1 - (float)h1) * 4096.f),
                        (_Float16)((r2 - (float)h2) * 4096.f),
                        (_Float16)((r3 - (float)h3) * 4096.f)};
    const int kt = c * 8 + kt_b;
    const size_t o = ((size_t)(mt * KTH + kt) * 64 + quad * 16 + w) * 8 + jb;
    *(half4_t*)(oh + o) = hv;
    *(half4_t*)(ol + o) = lv;
  }
}

// ---------------------------------------------------------------------------
// Fused: sum halves + bias + LN + ReLU  ->  head GEMM (+bp/bv)  ->  gumbel
// sampling. Block = 8 batch rows, 256 thr (4 waves).
// ---------------------------------------------------------------------------
__global__ __launch_bounds__(256) void head_fused_kernel(
    const float* __restrict__ x0, const float* __restrict__ x1,
    const float* __restrict__ b2, const float* __restrict__ g2,
    const float* __restrict__ be2,
    const float* __restrict__ Wc, const float* __restrict__ bp,
    const float* __restrict__ bv,
    const int* __restrict__ amask, const float* __restrict__ gum,
    float* __restrict__ out)
{
  __shared__ float Xs[8][1025];
  __shared__ float red[4][8][96];
  __shared__ float fl[8][96];
  __shared__ float rstat[16];
  const int t  = threadIdx.x;
  const int r0 = blockIdx.x * 8;
  const int wv = t >> 6, lane = t & 63;

  // stage: sum halves + pre-LN bias
#pragma unroll 4
  for (int i = 0; i < 32; ++i) {
    const int e = i * 256 + t;
    const int r = e >> 10, k = e & 1023;
    const size_t gi = (size_t)(r0 + r) * HDIM + k;
    Xs[r][k] = x0[gi] + x1[gi] + b2[k];
  }
  __syncthreads();

  // LN stats: wave wv handles rows wv and wv+4 (two-pass, matches reference)
#pragma unroll
  for (int rr = 0; rr < 2; ++rr) {
    const int row = wv + rr * 4;
    float s = 0.f;
#pragma unroll
    for (int ii = 0; ii < 16; ++ii) s += Xs[row][lane + 64 * ii];
#pragma unroll
    for (int o = 32; o; o >>= 1) s += __shfl_xor(s, o, 64);
    const float mean = s * (1.0f / HDIM);
    float s2 = 0.f;
#pragma unroll
    for (int ii = 0; ii < 16; ++ii) {
      const float d = Xs[row][lane + 64 * ii] - mean;
      s2 += d * d;
    }
#pragma unroll
    for (int o = 32; o; o >>= 1) s2 += __shfl_xor(s2, o, 64);
    if (lane == 0) {
      rstat[row] = mean;
      rstat[8 + row] = 1.0f / sqrtf(s2 * (1.0f / HDIM) + 1e-5f);
    }
  }
  __syncthreads();

  // normalize + relu in place
#pragma unroll 4
  for (int i = 0; i < 32; ++i) {
    const int e = i * 256 + t;
    const int r = e >> 10, k = e & 1023;
    Xs[r][k] = fmaxf(fmaf((Xs[r][k] - rstat[r]) * rstat[8 + r], g2[k], be2[k]), 0.f);
  }
  __syncthreads();

  // head GEMM: 16 tx (6 cols) x 4 ty (2 rows) x 4 kz
  const int tx = t & 15;
  const int ty = (t >> 4) & 3;
  const int kz = t >> 6;
  const int c0 = tx * 6;
  float acc[2][6] = {{0.f,0.f,0.f,0.f,0.f,0.f},{0.f,0.f,0.f,0.f,0.f,0.f}};
  const int kkend = kz * 256 + 256;
#pragma unroll 4
  for (int kk = kz * 256; kk < kkend; ++kk) {
    const float xa = Xs[ty * 2][kk];
    const float xb = Xs[ty * 2 + 1][kk];
    const float* wrow = Wc + (size_t)kk * 96 + c0;
    const float2 w01 = *(const float2*)(wrow);
    const float2 w23 = *(const float2*)(wrow + 2);
    const float2 w45 = *(const float2*)(wrow + 4);
    const float wvv[6] = {w01.x, w01.y, w23.x, w23.y, w45.x, w45.y};
#pragma unroll
    for (int j = 0; j < 6; ++j) {
      acc[0][j] = fmaf(xa, wvv[j], acc[0][j]);
      acc[1][j] = fmaf(xb, wvv[j], acc[1][j]);
    }
  }
#pragma unroll
  for (int r = 0; r < 2; ++r)
#pragma unroll
    for (int j = 0; j < 6; ++j) red[kz][ty * 2 + r][c0 + j] = acc[r][j];
  __syncthreads();

#pragma unroll
  for (int q = 0; q < 3; ++q) {
    const int e = t * 3 + q;
    const int row = e / 96, c = e % 96;
    const float sum = red[0][row][c] + red[1][row][c] + red[2][row][c] + red[3][row][c];
    if (c < 94) {
      const float vv = sum + bp[c];
      out[(size_t)(r0 + row) * NA2 + c] = vv;
      fl[row][c] = vv;
    } else if (c == 94) {
      out[VAL_OFF + r0 + row] = sum + bv[0];
    }
  }
  __syncthreads();

  // sampling: wave wv handles batch rows wv and wv+4
#pragma unroll
  for (int rr = 0; rr < 2; ++rr) {
    const int row = wv + rr * 4;
    const int b = r0 + row;
    const bool valid = lane < NACT;

    const float lg1 = valid ? fl[row][lane] : 0.f;
    const float lg2 = valid ? fl[row][NACT + lane] : 0.f;
    const int   mk1 = valid ? amask[(size_t)b * NA2 + lane] : 0;
    const int   mk2 = valid ? amask[(size_t)b * NA2 + NACT + lane] : 0;
    const float gu1 = valid ? gum[(size_t)b * NA2 + lane] : 0.f;
    const float gu2 = valid ? gum[(size_t)b * NA2 + NACT + lane] : 0.f;

    const float l1 = valid ? ((mk1 == 0) ? NEGC : lg1) : -INFINITY;
    float key = valid ? (l1 + gu1) : -INFINITY;
    int idx = lane;
#pragma unroll
    for (int o = 32; o; o >>= 1) {
      const float ok = __shfl_xor(key, o, 64);
      const int   oi = __shfl_xor(idx, o, 64);
      if (ok > key || (ok == key && oi < idx)) { key = ok; idx = oi; }
    }
    const int a1 = idx;

    float mx = l1;
#pragma unroll
    for (int o = 32; o; o >>= 1) mx = fmaxf(mx, __shfl_xor(mx, o, 64));
    float ex = valid ? expf(l1 - mx) : 0.f;
#pragma unroll
    for (int o = 32; o; o >>= 1) ex += __shfl_xor(ex, o, 64);
    const float logp1 = __shfl(l1, a1, 64) - (mx + logf(ex));

    int m2 = mk2;
    if (a1 >= 1 && a1 <= 6 && lane == a1) m2 = 0;
    if (a1 > 26 && a1 <= 46 && lane >= 27 && valid) m2 = 0;
    if (a1 == 0 && lane == 0) m2 = 0;
    int tot = m2;
#pragma unroll
    for (int o = 32; o; o >>= 1) tot += __shfl_xor(tot, o, 64);
    if (a1 == 0 && tot == 0 && lane == 0) m2 = 1;

    const float l2 = valid ? ((m2 == 0) ? NEGC : lg2) : -INFINITY;
    float key2 = valid ? (l2 + gu2) : -INFINITY;
    int idx2 = lane;
#pragma unroll
    for (int o = 32; o; o >>= 1) {
      const float ok = __shfl_xor(key2, o, 64);
      const int   oi = __shfl_xor(idx2, o, 64);
      if (ok > key2 || (ok == key2 && oi < idx2)) { key2 = ok; idx2 = oi; }
    }
    const int a2 = idx2;

    float mx2 = l2;
#pragma unroll
    for (int o = 32; o; o >>= 1) mx2 = fmaxf(mx2, __shfl_xor(mx2, o, 64));
    float ex2 = valid ? expf(l2 - mx2) : 0.f;
#pragma unroll
    for (int o = 32; o; o >>= 1) ex2 += __shfl_xor(ex2, o, 64);
    const float logp2 = __shfl(l2, a2, 64) - (mx2 + logf(ex2));

    if (lane == 0) {
      out[LP_OFF  + b * 2]     = logp1;
      out[LP_OFF  + b * 2 + 1] = logp2;
      out[ACT_OFF + b * 2]     = (float)a1;
      out[ACT_OFF + b * 2 + 1] = (float)a2;
    }
  }
}

// ---------------------------------------------------------------------------
extern "C" void kernel_launch(void* const* d_in, const int* in_sizes, int n_in,
                              void* d_out, int out_size, void* d_ws, size_t ws_size,
                              hipStream_t stream) {
  (void)in_sizes; (void)n_in; (void)out_size; (void)ws_size;
  const float* obs   = (const float*)d_in[0];
  const int*   amask = (const int*)  d_in[1];
  const float* gum   = (const float*)d_in[2];
  const float* W0    = (const float*)d_in[3];
  const float* b0    = (const float*)d_in[4];
  const float* g0    = (const float*)d_in[5];
  const float* be0   = (const float*)d_in[6];
  const float* W1    = (const float*)d_in[7];
  const float* b1    = (const float*)d_in[8];
  const float* g1    = (const float*)d_in[9];
  const float* be1   = (const float*)d_in[10];
  const float* W2    = (const float*)d_in[11];
  const float* b2    = (const float*)d_in[12];
  const float* g2    = (const float*)d_in[13];
  const float* be2   = (const float*)d_in[14];
  const float* Wp    = (const float*)d_in[15];
  const float* bp    = (const float*)d_in[16];
  const float* Wv    = (const float*)d_in[17];
  const float* bv    = (const float*)d_in[18];
  float* out = (float*)d_out;

  char* ws = (char*)d_ws;
  size_t off = 0;
  auto take = [&](size_t n) { char* p = ws + off; off += (n + 255) & ~(size_t)255; return p; };
  _Float16* w0h  = (_Float16*)take((size_t)HDIM * KP0 * 2);    // 14.7 MB
  _Float16* w0l  = (_Float16*)take((size_t)HDIM * KP0 * 2);    // 14.7 MB
  _Float16* w1h  = (_Float16*)take((size_t)HDIM * HDIM * 2);
  _Float16* w1l  = (_Float16*)take((size_t)HDIM * HDIM * 2);
  _Float16* w2h  = (_Float16*)take((size_t)HDIM * HDIM * 2);
  _Float16* w2l  = (_Float16*)take((size_t)HDIM * HDIM * 2);
  float*    xf   = (float*)   take((size_t)2 * BATCH * HDIM * 4); // 33.6 MB (2 halves)
  float*    wc   = (float*)   take((size_t)HDIM * 96 * 4);
  // activation f16 planes alias the (dead after GEMM0) W0 plane region
  _Float16* xph  = w0h;
  _Float16* xpl  = w0l;
  float* xf1 = xf + (size_t)BATCH * HDIM;

  // all weight conversions + head pack in ONE launch (block-range dispatch)
  prep_kernel<<<1792 + 256 + 256 + 384, 256, 0, stream>>>(
      W0, w0h, w0l, W1, w1h, w1l, W2, w2h, w2l, Wp, Wv, wc);

  // layer 0: A (obs fp32) decomposed in-kernel; 112 k-tiles per z-half
  gemm_obs_kernel<<<dim3(8, 64, 2), 512, 0, stream>>>(obs, w0h, w0l, xf, KT0 / 2);
  ln_relu_f16_frag_kernel<<<BATCH / 16, 1024, 0, stream>>>(xf, xf1, b0, g0, be0, xph, xpl);

  // layer 1: 16 k-tiles per z-half
  gemm_frag2_kernel<<<dim3(8, 64, 2), 512, 0, stream>>>(xph, xpl, w1h, w1l, xf, KTH, KTH / 2);
  ln_relu_f16_frag_kernel<<<BATCH / 16, 1024, 0, stream>>>(xf, xf1, b1, g1, be1, xph, xpl);

  // layer 2
  gemm_frag2_kernel<<<dim3(8, 64, 2), 512, 0, stream>>>(xph, xpl, w2h, w2l, xf, KTH, KTH / 2);

  // fused final-LN + heads + sampling
  head_fused_kernel<<<BATCH / 8, 256, 0, stream>>>(
      xf, xf1, b2, g2, be2, wc, bp, bv, amask, gum, out);
}

// Round 6
// 531.333 us; speedup vs baseline: 1.4422x; 1.4422x over previous
//
#include <hip/hip_runtime.h>
#include <math.h>

#define BATCH 4096
#define HDIM  1024
#define KDIM0 7150
#define KP0   7168
#define KT0   224          // KP0/32
#define KTH   32           // HDIM/32
#define NACT  47
#define NA2   94
#define NEGC  -1000000000.0f

// output layout (floats): logits [0,385024), logp [385024,393216),
// actions [393216,401408), value [401408,405504)
#define LP_OFF  385024
#define ACT_OFF 393216
#define VAL_OFF 401408

typedef _Float16 half8_t  __attribute__((ext_vector_type(8)));
typedef _Float16 half4_t  __attribute__((ext_vector_type(4)));
typedef float    float4_t __attribute__((ext_vector_type(4)));

#define GLOAD16(gp, lp) __builtin_amdgcn_global_load_lds( \
    (__attribute__((address_space(1))) void*)(gp), \
    (__attribute__((address_space(3))) void*)(lp), 16, 0, 0)

// Fragment-tile order for a [R][Kp] f16 plane (R = rows of A / cols of W^T):
//   tile = rt*KT + kt ; within tile: lane = quad*16 + (r%16), quad=(k%32)/8,
//   halfs addr = tile*512 + lane*8 + (k%8).  (mfma_f32_16x16x32_f16 layout)

// ---------------------------------------------------------------------------
// Weight convert body: W[K][HDIM] fp32 -> hi/lo f16 planes of W^T, frag order.
// Global loads vectorized to float4 (W rows 16B-aligned: HDIM=1024, n0%64==0).
// LDS stores stay scalar: stride 65 keeps the repack-phase reads conflict-free
// (any float4-aligned stride would give a 4-way quad conflict).
// ---------------------------------------------------------------------------
__device__ __forceinline__ void wconv_body(
    const float* __restrict__ W, _Float16* __restrict__ Wh,
    _Float16* __restrict__ Wl, int K, int KT, int bxk, int byn)
{
  __shared__ float T[64][65];
  const int k0 = bxk * 64, n0 = byn * 64, t = threadIdx.x;
#pragma unroll
  for (int p = 0; p < 4; ++p) {
    const int idx = p * 256 + t;           // 1024 float4 slots = 64x64 floats
    const int r = idx >> 4, c4 = (idx & 15) * 4;
    float4 vv = make_float4(0.f, 0.f, 0.f, 0.f);
    if (k0 + r < K)                        // K-tail cuts whole rows
      vv = *(const float4*)(W + (size_t)(k0 + r) * HDIM + n0 + c4);
    T[r][c4] = vv.x; T[r][c4 + 1] = vv.y;
    T[r][c4 + 2] = vv.z; T[r][c4 + 3] = vv.w;
  }
  __syncthreads();
#pragma unroll
  for (int ss = 0; ss < 2; ++ss) {
    const int s    = ss * 256 + t;
    const int tile = s >> 6;            // 0..7 = 2 kt x 4 nt
    const int ktl  = tile >> 2, ntl = tile & 3;
    const int lane = s & 63;
    const int quad = lane >> 4, nr = lane & 15;
    half8_t h, l;
#pragma unroll
    for (int j = 0; j < 8; ++j) {
      const float v = T[ktl * 32 + quad * 8 + j][ntl * 16 + nr];
      const _Float16 hh = (_Float16)v;
      h[j] = hh;
      l[j] = (_Float16)((v - (float)hh) * 4096.f);
    }
    const size_t o = ((size_t)((n0 / 16 + ntl) * KT + (k0 / 32 + ktl)) * 64 + lane) * 8;
    *(half8_t*)(Wh + o) = h;
    *(half8_t*)(Wl + o) = l;
  }
}

// ---------------------------------------------------------------------------
// Merged prep: one launch does wconv(W0) + wconv(W1) + wconv(W2) + pack_wcat.
// Block-range dispatch: [0,1792) W0, [1792,2048) W1, [2048,2304) W2,
// [2304,2688) pack.
// ---------------------------------------------------------------------------
__global__ __launch_bounds__(256) void prep_kernel(
    const float* __restrict__ W0, _Float16* __restrict__ w0h, _Float16* __restrict__ w0l,
    const float* __restrict__ W1, _Float16* __restrict__ w1h, _Float16* __restrict__ w1l,
    const float* __restrict__ W2, _Float16* __restrict__ w2h, _Float16* __restrict__ w2l,
    const float* __restrict__ Wp, const float* __restrict__ Wv,
    float* __restrict__ Wc)
{
  int id = blockIdx.x;
  if (id < 1792) {                       // W0: 112 k-chunks x 16 n-chunks
    wconv_body(W0, w0h, w0l, KDIM0, KT0, id % 112, id / 112);
    return;
  }
  id -= 1792;
  if (id < 256) {                        // W1: 16 x 16
    wconv_body(W1, w1h, w1l, HDIM, KTH, id % 16, id / 16);
    return;
  }
  id -= 256;
  if (id < 256) {                        // W2: 16 x 16
    wconv_body(W2, w2h, w2l, HDIM, KTH, id % 16, id / 16);
    return;
  }
  id -= 256;                             // pack Wcat[1024][96]
  const int i = id * 256 + threadIdx.x;
  const int k = i / 96, c = i % 96;
  float v = 0.f;
  if (c < 94)       v = Wp[(size_t)k * 94 + c];
  else if (c == 94) v = Wv[k];
  Wc[i] = v;
}

// ---------------------------------------------------------------------------
// f16x3 split GEMM for layer 0, A read DIRECTLY from fp32 obs (adecomp fused).
// 2-phase double-buffered schedule: stage tile t+1 (W via global_load_lds,
// A via fp32 reg load -> in-register hi/lo split -> ds_write) BEFORE the MFMA
// phase on tile t; one __syncthreads per k-tile. A regs pipelined 2-deep.
// BM=128 (required: MFMA phase must cover ~900cy HBM latency — BM=64 regressed
// 2.4x, round-5). BK=32, LDS 2x32KB -> 2 blocks/CU.
// ---------------------------------------------------------------------------
__global__ __launch_bounds__(512, 4) void gemm_obs_kernel(
    const float* __restrict__ A,
    const _Float16* __restrict__ Wh, const _Float16* __restrict__ Wl,
    float* __restrict__ C, int ktsplit)
{
  __shared__ _Float16 As[2][2][8][512];   // [buf][plane][mt][frag]
  __shared__ _Float16 Ws[2][2][8][512];   // [buf][plane][nt][frag]
  // XCD-aware bijective swizzle: 512 blocks, 8 XCDs, chunk=64
  const int f  = blockIdx.x + 8 * (blockIdx.y + 32 * blockIdx.z);
  const int nf = (f & 7) * 64 + (f >> 3);
  const int bx = nf & 7, by = (nf >> 3) & 31, bz = nf >> 8;

  const int t    = threadIdx.x;
  const int lane = t & 63;
  const int w    = t >> 6;
  const int nt0  = bx * 8;
  const int mt0  = by * 8;
  const int ktb  = bz * ktsplit;
  const int nit  = ktsplit;            // k-tiles per block (BK=32), even
  const int l15  = lane & 15, quad = lane >> 4;
  const int wmi  = (w >> 2) * 4;
  const int wni  = (w & 3) * 2;

  // wave w stages A m-tile mt0+w (fp32) and W n-tile nt0+w (planes)
  const float* aRow = A + (size_t)((mt0 + w) * 16 + l15) * KDIM0 + quad * 8;
  const _Float16* wS0 = Wh + (size_t)(nt0 + w) * KT0 * 512 + lane * 8;
  const _Float16* wS1 = Wl + (size_t)(nt0 + w) * KT0 * 512 + lane * 8;

  struct AF8 { float v[8]; };
  auto loadA = [&](int kt) {
    AF8 r;
    const int kg = kt * 32 + quad * 8;
    const float* src = aRow + (size_t)kt * 32;
    if (kg + 8 <= KDIM0) {
#pragma unroll
      for (int c = 0; c < 4; ++c) {       // 8B-aligned only (KDIM0 odd stride)
        const float2 p = *(const float2*)(src + c * 2);
        r.v[c * 2] = p.x; r.v[c * 2 + 1] = p.y;
      }
    } else {
#pragma unroll
      for (int j = 0; j < 8; ++j)
        r.v[j] = (kg + j < KDIM0) ? src[j] : 0.f;
    }
    return r;
  };
  auto gw = [&](int kt, int buf) {
    GLOAD16(wS0 + (size_t)kt * 512, &Ws[buf][0][w][0]);
    GLOAD16(wS1 + (size_t)kt * 512, &Ws[buf][1][w][0]);
  };
  auto convst = [&](const AF8& a, int buf) {
    half8_t h, l;
#pragma unroll
    for (int j = 0; j < 8; ++j) {
      const float v = a.v[j];
      const _Float16 hh = (_Float16)v;
      h[j] = hh;
      l[j] = (_Float16)((v - (float)hh) * 4096.f);
    }
    *(half8_t*)&As[buf][0][w][lane * 8] = h;
    *(half8_t*)&As[buf][1][w][lane * 8] = l;
  };

  float4_t acc[4][2], accx[4][2];
#pragma unroll
  for (int i = 0; i < 4; ++i)
#pragma unroll
    for (int j = 0; j < 2; ++j) {
      acc[i][j]  = (float4_t){0.f, 0.f, 0.f, 0.f};
      accx[i][j] = (float4_t){0.f, 0.f, 0.f, 0.f};
    }

  auto mm = [&](int buf) {
    half8_t ah[4], al[4], wh[2], wl[2];
#pragma unroll
    for (int i = 0; i < 4; ++i) {
      ah[i] = *(const half8_t*)&As[buf][0][wmi + i][lane * 8];
      al[i] = *(const half8_t*)&As[buf][1][wmi + i][lane * 8];
    }
#pragma unroll
    for (int j = 0; j < 2; ++j) {
      wh[j] = *(const half8_t*)&Ws[buf][0][wni + j][lane * 8];
      wl[j] = *(const half8_t*)&Ws[buf][1][wni + j][lane * 8];
    }
#pragma unroll
    for (int i = 0; i < 4; ++i)
#pragma unroll
      for (int j = 0; j < 2; ++j) {
        acc[i][j]  = __builtin_amdgcn_mfma_f32_16x16x32_f16(ah[i], wh[j], acc[i][j], 0, 0, 0);
        accx[i][j] = __builtin_amdgcn_mfma_f32_16x16x32_f16(ah[i], wl[j], accx[i][j], 0, 0, 0);
        accx[i][j] = __builtin_amdgcn_mfma_f32_16x16x32_f16(al[i], wh[j], accx[i][j], 0, 0, 0);
      }
  };

  // prologue: tile0 staged into buf0; A regs for tiles 0,1 in flight
  AF8 vaE = loadA(ktb + 0);
  AF8 vaO = loadA(ktb + 1);
  gw(ktb + 0, 0);
  convst(vaE, 0);
  __syncthreads();

  for (int it = 0; it < nit; it += 2) {
    // iter it (even tile, buf0): stage tile it+1 -> buf1, prefetch A it+2.
    // A loads issued BEFORE the convert so the convert VALU covers them.
    gw(ktb + it + 1, 1);
    if (it + 2 < nit) vaE = loadA(ktb + it + 2);
    convst(vaO, 1);
    mm(0);
    __syncthreads();
    // iter it+1 (odd tile, buf1): stage tile it+2 -> buf0, prefetch A it+3
    if (it + 2 < nit) gw(ktb + it + 2, 0);
    if (it + 3 < nit) vaO = loadA(ktb + it + 3);
    if (it + 2 < nit) convst(vaE, 0);
    mm(1);
    __syncthreads();
  }

  float* Cb = C + (size_t)bz * ((size_t)BATCH * HDIM);
  const float sc = 1.0f / 4096.0f;
#pragma unroll
  for (int i = 0; i < 4; ++i) {
    const int row0 = (mt0 + wmi + i) * 16 + quad * 4;
#pragma unroll
    for (int j = 0; j < 2; ++j) {
      const int col = (nt0 + wni + j) * 16 + l15;
      float* cp = Cb + (size_t)row0 * HDIM + col;
#pragma unroll
      for (int r = 0; r < 4; ++r)
        cp[(size_t)r * HDIM] = acc[i][j][r] + accx[i][j][r] * sc;
    }
  }
}

// ---------------------------------------------------------------------------
// f16x3 split GEMM (layers 1/2), fragment-order planes, 2-phase double-
// buffered schedule: stage tile t+1 (4x global_load_lds) before MFMA on tile
// t; one __syncthreads per k-tile. BK=32, LDS 2x32KB. XCD-swizzled grid.
// ---------------------------------------------------------------------------
__global__ __launch_bounds__(512, 4) void gemm_frag2_kernel(
    const _Float16* __restrict__ Ah, const _Float16* __restrict__ Al,
    const _Float16* __restrict__ Wh, const _Float16* __restrict__ Wl,
    float* __restrict__ C, int KT, int ktsplit)
{
  __shared__ _Float16 As[2][2][8][512];   // [buf][plane][mt][frag]
  __shared__ _Float16 Ws[2][2][8][512];
  const int f  = blockIdx.x + 8 * (blockIdx.y + 32 * blockIdx.z);
  const int nf = (f & 7) * 64 + (f >> 3);
  const int bx = nf & 7, by = (nf >> 3) & 31, bz = nf >> 8;

  const int t    = threadIdx.x;
  const int lane = t & 63;
  const int w    = t >> 6;
  const int nt0  = bx * 8;
  const int mt0  = by * 8;
  const int ktb  = bz * ktsplit;
  const int nit  = ktsplit;            // k-tiles per block (BK=32), even
  const int l15  = lane & 15, quad = lane >> 4;
  const int wmi  = (w >> 2) * 4;
  const int wni  = (w & 3) * 2;

  const _Float16* aS0 = Ah + (size_t)(mt0 + w) * KT * 512 + lane * 8;
  const _Float16* aS1 = Al + (size_t)(mt0 + w) * KT * 512 + lane * 8;
  const _Float16* wS0 = Wh + (size_t)(nt0 + w) * KT * 512 + lane * 8;
  const _Float16* wS1 = Wl + (size_t)(nt0 + w) * KT * 512 + lane * 8;

  auto st = [&](int kt, int buf) {
    GLOAD16(aS0 + (size_t)kt * 512, &As[buf][0][w][0]);
    GLOAD16(aS1 + (size_t)kt * 512, &As[buf][1][w][0]);
    GLOAD16(wS0 + (size_t)kt * 512, &Ws[buf][0][w][0]);
    GLOAD16(wS1 + (size_t)kt * 512, &Ws[buf][1][w][0]);
  };

  float4_t acc[4][2], accx[4][2];
#pragma unroll
  for (int i = 0; i < 4; ++i)
#pragma unroll
    for (int j = 0; j < 2; ++j) {
      acc[i][j]  = (float4_t){0.f, 0.f, 0.f, 0.f};
      accx[i][j] = (float4_t){0.f, 0.f, 0.f, 0.f};
    }

  auto mm = [&](int buf) {
    half8_t ah[4], al[4], wh[2], wl[2];
#pragma unroll
    for (int i = 0; i < 4; ++i) {
      ah[i] = *(const half8_t*)&As[buf][0][wmi + i][lane * 8];
      al[i] = *(const half8_t*)&As[buf][1][wmi + i][lane * 8];
    }
#pragma unroll
    for (int j = 0; j < 2; ++j) {
      wh[j] = *(const half8_t*)&Ws[buf][0][wni + j][lane * 8];
      wl[j] = *(const half8_t*)&Ws[buf][1][wni + j][lane * 8];
    }
#pragma unroll
    for (int i = 0; i < 4; ++i)
#pragma unroll
      for (int j = 0; j < 2; ++j) {
        acc[i][j]  = __builtin_amdgcn_mfma_f32_16x16x32_f16(ah[i], wh[j], acc[i][j], 0, 0, 0);
        accx[i][j] = __builtin_amdgcn_mfma_f32_16x16x32_f16(ah[i], wl[j], accx[i][j], 0, 0, 0);
        accx[i][j] = __builtin_amdgcn_mfma_f32_16x16x32_f16(al[i], wh[j], accx[i][j], 0, 0, 0);
      }
  };

  st(ktb, 0);
  __syncthreads();
  for (int it = 0; it < nit; it += 2) {
    st(ktb + it + 1, 1);
    mm(0);
    __syncthreads();
    if (it + 2 < nit) st(ktb + it + 2, 0);
    mm(1);
    __syncthreads();
  }

  float* Cb = C + (size_t)bz * ((size_t)BATCH * HDIM);
  const float sc = 1.0f / 4096.0f;
#pragma unroll
  for (int i = 0; i < 4; ++i) {
    const int row0 = (mt0 + wmi + i) * 16 + quad * 4;
#pragma unroll
    for (int j = 0; j < 2; ++j) {
      const int col = (nt0 + wni + j) * 16 + l15;
      float* cp = Cb + (size_t)row0 * HDIM + col;
#pragma unroll
      for (int r = 0; r < 4; ++r)
        cp[(size_t)r * HDIM] = acc[i][j][r] + accx[i][j][r] * sc;
    }
  }
}

// ---------------------------------------------------------------------------
// sum halves + bias + LayerNorm + ReLU -> hi/lo f16 planes (fragment order).
// 1024 thr = 16 waves; wave w = row mt*16+w, wave-local reductions.
// ---------------------------------------------------------------------------
__global__ __launch_bounds__(1024) void ln_relu_f16_frag_kernel(
    const float* __restrict__ x0, const float* __restrict__ x1,
    const float* __restrict__ bias,
    const float* __restrict__ g, const float* __restrict__ be,
    _Float16* __restrict__ oh, _Float16* __restrict__ ol)
{
  const int t = threadIdx.x;
  const int w = t >> 6, lane = t & 63;
  const int mt = blockIdx.x;
  const float* xr0 = x0 + (size_t)(mt * 16 + w) * HDIM;
  const float* xr1 = x1 + (size_t)(mt * 16 + w) * HDIM;

  float4 v[4];
  float s = 0.f;
#pragma unroll
  for (int c = 0; c < 4; ++c) {
    const int k = c * 256 + lane * 4;
    const float4 a = *(const float4*)(xr0 + k);
    const float4 b = *(const float4*)(xr1 + k);
    const float4 bb = *(const float4*)(bias + k);
    v[c].x = a.x + b.x + bb.x; v[c].y = a.y + b.y + bb.y;
    v[c].z = a.z + b.z + bb.z; v[c].w = a.w + b.w + bb.w;
    s += (v[c].x + v[c].y) + (v[c].z + v[c].w);
  }
#pragma unroll
  for (int o = 32; o; o >>= 1) s += __shfl_xor(s, o, 64);
  const float mean = s * (1.0f / HDIM);

  float s2 = 0.f;
#pragma unroll
  for (int c = 0; c < 4; ++c) {
    v[c].x -= mean; v[c].y -= mean; v[c].z -= mean; v[c].w -= mean;
    s2 += (v[c].x * v[c].x + v[c].y * v[c].y) + (v[c].z * v[c].z + v[c].w * v[c].w);
  }
#pragma unroll
  for (int o = 32; o; o >>= 1) s2 += __shfl_xor(s2, o, 64);
  const float inv = 1.0f / sqrtf(s2 * (1.0f / HDIM) + 1e-5f);

  const int kt_b  = lane >> 3;
  const int quad  = (lane >> 1) & 3;
  const int jb    = (lane & 1) * 4;
#pragma unroll
  for (int c = 0; c < 4; ++c) {
    const int k = c * 256 + lane * 4;
    const float4 gg = *(const float4*)(g + k);
    const float4 ee = *(const float4*)(be + k);
    float r0 = fmaxf(fmaf(v[c].x * inv, gg.x, ee.x), 0.f);
    float r1 = fmaxf(fmaf(v[c].y * inv, gg.y, ee.y), 0.f);
    float r2 = fmaxf(fmaf(v[c].z * inv, gg.z, ee.z), 0.f);
    float r3 = fmaxf(fmaf(v[c].w * inv, gg.w, ee.w), 0.f);
    const _Float16 h0 = (_Float16)r0, h1 = (_Float16)r1, h2 = (_Float16)r2, h3 = (_Float16)r3;
    const half4_t hv = {h0, h1, h2, h3};
    const half4_t lv = {(_Float16)((r0 - (float)h0) * 4096.f),
                        (_Float16)((r1 - (float)h1) * 4096.f),
                        (_Float16)((r2 - (float)h2) * 4096.f),
                        (_Float16)((r3 - (float)h3) * 4096.f)};
    const int kt = c * 8 + kt_b;
    const size_t o = ((size_t)(mt * KTH + kt) * 64 + quad * 16 + w) * 8 + jb;
    *(half4_t*)(oh + o) = hv;
    *(half4_t*)(ol + o) = lv;
  }
}

// ---------------------------------------------------------------------------
// Fused: sum halves + bias + LN + ReLU  ->  head GEMM (+bp/bv)  ->  gumbel
// sampling. Block = 8 batch rows, 256 thr (4 waves).
// ---------------------------------------------------------------------------
__global__ __launch_bounds__(256) void head_fused_kernel(
    const float* __restrict__ x0, const float* __restrict__ x1,
    const float* __restrict__ b2, const float* __restrict__ g2,
    const float* __restrict__ be2,
    const float* __restrict__ Wc, const float* __restrict__ bp,
    const float* __restrict__ bv,
    const int* __restrict__ amask, const float* __restrict__ gum,
    float* __restrict__ out)
{
  __shared__ float Xs[8][1025];
  __shared__ float red[4][8][96];
  __shared__ float fl[8][96];
  __shared__ float rstat[16];
  const int t  = threadIdx.x;
  const int r0 = blockIdx.x * 8;
  const int wv = t >> 6, lane = t & 63;

  // stage: sum halves + pre-LN bias
#pragma unroll 4
  for (int i = 0; i < 32; ++i) {
    const int e = i * 256 + t;
    const int r = e >> 10, k = e & 1023;
    const size_t gi = (size_t)(r0 + r) * HDIM + k;
    Xs[r][k] = x0[gi] + x1[gi] + b2[k];
  }
  __syncthreads();

  // LN stats: wave wv handles rows wv and wv+4 (two-pass, matches reference)
#pragma unroll
  for (int rr = 0; rr < 2; ++rr) {
    const int row = wv + rr * 4;
    float s = 0.f;
#pragma unroll
    for (int ii = 0; ii < 16; ++ii) s += Xs[row][lane + 64 * ii];
#pragma unroll
    for (int o = 32; o; o >>= 1) s += __shfl_xor(s, o, 64);
    const float mean = s * (1.0f / HDIM);
    float s2 = 0.f;
#pragma unroll
    for (int ii = 0; ii < 16; ++ii) {
      const float d = Xs[row][lane + 64 * ii] - mean;
      s2 += d * d;
    }
#pragma unroll
    for (int o = 32; o; o >>= 1) s2 += __shfl_xor(s2, o, 64);
    if (lane == 0) {
      rstat[row] = mean;
      rstat[8 + row] = 1.0f / sqrtf(s2 * (1.0f / HDIM) + 1e-5f);
    }
  }
  __syncthreads();

  // normalize + relu in place
#pragma unroll 4
  for (int i = 0; i < 32; ++i) {
    const int e = i * 256 + t;
    const int r = e >> 10, k = e & 1023;
    Xs[r][k] = fmaxf(fmaf((Xs[r][k] - rstat[r]) * rstat[8 + r], g2[k], be2[k]), 0.f);
  }
  __syncthreads();

  // head GEMM: 16 tx (6 cols) x 4 ty (2 rows) x 4 kz
  const int tx = t & 15;
  const int ty = (t >> 4) & 3;
  const int kz = t >> 6;
  const int c0 = tx * 6;
  float acc[2][6] = {{0.f,0.f,0.f,0.f,0.f,0.f},{0.f,0.f,0.f,0.f,0.f,0.f}};
  const int kkend = kz * 256 + 256;
#pragma unroll 4
  for (int kk = kz * 256; kk < kkend; ++kk) {
    const float xa = Xs[ty * 2][kk];
    const float xb = Xs[ty * 2 + 1][kk];
    const float* wrow = Wc + (size_t)kk * 96 + c0;
    const float2 w01 = *(const float2*)(wrow);
    const float2 w23 = *(const float2*)(wrow + 2);
    const float2 w45 = *(const float2*)(wrow + 4);
    const float wvv[6] = {w01.x, w01.y, w23.x, w23.y, w45.x, w45.y};
#pragma unroll
    for (int j = 0; j < 6; ++j) {
      acc[0][j] = fmaf(xa, wvv[j], acc[0][j]);
      acc[1][j] = fmaf(xb, wvv[j], acc[1][j]);
    }
  }
#pragma unroll
  for (int r = 0; r < 2; ++r)
#pragma unroll
    for (int j = 0; j < 6; ++j) red[kz][ty * 2 + r][c0 + j] = acc[r][j];
  __syncthreads();

#pragma unroll
  for (int q = 0; q < 3; ++q) {
    const int e = t * 3 + q;
    const int row = e / 96, c = e % 96;
    const float sum = red[0][row][c] + red[1][row][c] + red[2][row][c] + red[3][row][c];
    if (c < 94) {
      const float vv = sum + bp[c];
      out[(size_t)(r0 + row) * NA2 + c] = vv;
      fl[row][c] = vv;
    } else if (c == 94) {
      out[VAL_OFF + r0 + row] = sum + bv[0];
    }
  }
  __syncthreads();

  // sampling: wave wv handles batch rows wv and wv+4
#pragma unroll
  for (int rr = 0; rr < 2; ++rr) {
    const int row = wv + rr * 4;
    const int b = r0 + row;
    const bool valid = lane < NACT;

    const float lg1 = valid ? fl[row][lane] : 0.f;
    const float lg2 = valid ? fl[row][NACT + lane] : 0.f;
    const int   mk1 = valid ? amask[(size_t)b * NA2 + lane] : 0;
    const int   mk2 = valid ? amask[(size_t)b * NA2 + NACT + lane] : 0;
    const float gu1 = valid ? gum[(size_t)b * NA2 + lane] : 0.f;
    const float gu2 = valid ? gum[(size_t)b * NA2 + NACT + lane] : 0.f;

    const float l1 = valid ? ((mk1 == 0) ? NEGC : lg1) : -INFINITY;
    float key = valid ? (l1 + gu1) : -INFINITY;
    int idx = lane;
#pragma unroll
    for (int o = 32; o; o >>= 1) {
      const float ok = __shfl_xor(key, o, 64);
      const int   oi = __shfl_xor(idx, o, 64);
      if (ok > key || (ok == key && oi < idx)) { key = ok; idx = oi; }
    }
    const int a1 = idx;

    float mx = l1;
#pragma unroll
    for (int o = 32; o; o >>= 1) mx = fmaxf(mx, __shfl_xor(mx, o, 64));
    float ex = valid ? expf(l1 - mx) : 0.f;
#pragma unroll
    for (int o = 32; o; o >>= 1) ex += __shfl_xor(ex, o, 64);
    const float logp1 = __shfl(l1, a1, 64) - (mx + logf(ex));

    int m2 = mk2;
    if (a1 >= 1 && a1 <= 6 && lane == a1) m2 = 0;
    if (a1 > 26 && a1 <= 46 && lane >= 27 && valid) m2 = 0;
    if (a1 == 0 && lane == 0) m2 = 0;
    int tot = m2;
#pragma unroll
    for (int o = 32; o; o >>= 1) tot += __shfl_xor(tot, o, 64);
    if (a1 == 0 && tot == 0 && lane == 0) m2 = 1;

    const float l2 = valid ? ((m2 == 0) ? NEGC : lg2) : -INFINITY;
    float key2 = valid ? (l2 + gu2) : -INFINITY;
    int idx2 = lane;
#pragma unroll
    for (int o = 32; o; o >>= 1) {
      const float ok = __shfl_xor(key2, o, 64);
      const int   oi = __shfl_xor(idx2, o, 64);
      if (ok > key2 || (ok == key2 && oi < idx2)) { key2 = ok; idx2 = oi; }
    }
    const int a2 = idx2;

    float mx2 = l2;
#pragma unroll
    for (int o = 32; o; o >>= 1) mx2 = fmaxf(mx2, __shfl_xor(mx2, o, 64));
    float ex2 = valid ? expf(l2 - mx2) : 0.f;
#pragma unroll
    for (int o = 32; o; o >>= 1) ex2 += __shfl_xor(ex2, o, 64);
    const float logp2 = __shfl(l2, a2, 64) - (mx2 + logf(ex2));

    if (lane == 0) {
      out[LP_OFF  + b * 2]     = logp1;
      out[LP_OFF  + b * 2 + 1] = logp2;
      out[ACT_OFF + b * 2]     = (float)a1;
      out[ACT_OFF + b * 2 + 1] = (float)a2;
    }
  }
}

// ---------------------------------------------------------------------------
extern "C" void kernel_launch(void* const* d_in, const int* in_sizes, int n_in,
                              void* d_out, int out_size, void* d_ws, size_t ws_size,
                              hipStream_t stream) {
  (void)in_sizes; (void)n_in; (void)out_size; (void)ws_size;
  const float* obs   = (const float*)d_in[0];
  const int*   amask = (const int*)  d_in[1];
  const float* gum   = (const float*)d_in[2];
  const float* W0    = (const float*)d_in[3];
  const float* b0    = (const float*)d_in[4];
  const float* g0    = (const float*)d_in[5];
  const float* be0   = (const float*)d_in[6];
  const float* W1    = (const float*)d_in[7];
  const float* b1    = (const float*)d_in[8];
  const float* g1    = (const float*)d_in[9];
  const float* be1   = (const float*)d_in[10];
  const float* W2    = (const float*)d_in[11];
  const float* b2    = (const float*)d_in[12];
  const float* g2    = (const float*)d_in[13];
  const float* be2   = (const float*)d_in[14];
  const float* Wp    = (const float*)d_in[15];
  const float* bp    = (const float*)d_in[16];
  const float* Wv    = (const float*)d_in[17];
  const float* bv    = (const float*)d_in[18];
  float* out = (float*)d_out;

  char* ws = (char*)d_ws;
  size_t off = 0;
  auto take = [&](size_t n) { char* p = ws + off; off += (n + 255) & ~(size_t)255; return p; };
  _Float16* w0h  = (_Float16*)take((size_t)HDIM * KP0 * 2);    // 14.7 MB
  _Float16* w0l  = (_Float16*)take((size_t)HDIM * KP0 * 2);    // 14.7 MB
  _Float16* w1h  = (_Float16*)take((size_t)HDIM * HDIM * 2);
  _Float16* w1l  = (_Float16*)take((size_t)HDIM * HDIM * 2);
  _Float16* w2h  = (_Float16*)take((size_t)HDIM * HDIM * 2);
  _Float16* w2l  = (_Float16*)take((size_t)HDIM * HDIM * 2);
  float*    xf   = (float*)   take((size_t)2 * BATCH * HDIM * 4); // 33.6 MB (2 halves)
  float*    wc   = (float*)   take((size_t)HDIM * 96 * 4);
  // activation f16 planes alias the (dead after GEMM0) W0 plane region
  _Float16* xph  = w0h;
  _Float16* xpl  = w0l;
  float* xf1 = xf + (size_t)BATCH * HDIM;

  // all weight conversions + head pack in ONE launch (block-range dispatch)
  prep_kernel<<<1792 + 256 + 256 + 384, 256, 0, stream>>>(
      W0, w0h, w0l, W1, w1h, w1l, W2, w2h, w2l, Wp, Wv, wc);

  // layer 0: A (obs fp32) decomposed in-kernel; 112 k-tiles per z-half
  gemm_obs_kernel<<<dim3(8, 32, 2), 512, 0, stream>>>(obs, w0h, w0l, xf, KT0 / 2);
  ln_relu_f16_frag_kernel<<<BATCH / 16, 1024, 0, stream>>>(xf, xf1, b0, g0, be0, xph, xpl);

  // layer 1: 16 k-tiles per z-half
  gemm_frag2_kernel<<<dim3(8, 32, 2), 512, 0, stream>>>(xph, xpl, w1h, w1l, xf, KTH, KTH / 2);
  ln_relu_f16_frag_kernel<<<BATCH / 16, 1024, 0, stream>>>(xf, xf1, b1, g1, be1, xph, xpl);

  // layer 2
  gemm_frag2_kernel<<<dim3(8, 32, 2), 512, 0, stream>>>(xph, xpl, w2h, w2l, xf, KTH, KTH / 2);

  // fused final-LN + heads + sampling
  head_fused_kernel<<<BATCH / 8, 256, 0, stream>>>(
      xf, xf1, b2, g2, be2, wc, bp, bv, amask, gum, out);
}

// Round 8
// 496.523 us; speedup vs baseline: 1.5433x; 1.0701x over previous
//
#include <hip/hip_runtime.h>
#include <math.h>

#define BATCH 4096
#define HDIM  1024
#define KDIM0 7150
#define KP0   7168
#define KT0   224          // KP0/32
#define KTH   32           // HDIM/32
#define NACT  47
#define NA2   94
#define NEGC  -1000000000.0f

// output layout (floats): logits [0,385024), logp [385024,393216),
// actions [393216,401408), value [401408,405504)
#define LP_OFF  385024
#define ACT_OFF 393216
#define VAL_OFF 401408

typedef _Float16 half8_t  __attribute__((ext_vector_type(8)));
typedef _Float16 half4_t  __attribute__((ext_vector_type(4)));
typedef float    float4_t __attribute__((ext_vector_type(4)));

#define GLOAD16(gp, lp) __builtin_amdgcn_global_load_lds( \
    (__attribute__((address_space(1))) void*)(gp), \
    (__attribute__((address_space(3))) void*)(lp), 16, 0, 0)

// Fragment-tile order for a [R][Kp] f16 plane (R = rows of A / cols of W^T):
//   tile = rt*KT + kt ; within tile: lane = quad*16 + (r%16), quad=(k%32)/8,
//   halfs addr = tile*512 + lane*8 + (k%8).  (mfma_f32_16x16x32_f16 layout)

// ---------------------------------------------------------------------------
// Weight convert body: W[K][HDIM] fp32 -> hi/lo f16 planes of W^T, frag order.
// ---------------------------------------------------------------------------
__device__ __forceinline__ void wconv_body(
    const float* __restrict__ W, _Float16* __restrict__ Wh,
    _Float16* __restrict__ Wl, int K, int KT, int bxk, int byn)
{
  __shared__ float T[64][65];
  const int k0 = bxk * 64, n0 = byn * 64, t = threadIdx.x;
#pragma unroll
  for (int p = 0; p < 16; ++p) {
    const int idx = p * 256 + t;
    const int r = idx >> 6, c = idx & 63;
    T[r][c] = (k0 + r < K) ? W[(size_t)(k0 + r) * HDIM + n0 + c] : 0.f;
  }
  __syncthreads();
#pragma unroll
  for (int ss = 0; ss < 2; ++ss) {
    const int s    = ss * 256 + t;
    const int tile = s >> 6;            // 0..7 = 2 kt x 4 nt
    const int ktl  = tile >> 2, ntl = tile & 3;
    const int lane = s & 63;
    const int quad = lane >> 4, nr = lane & 15;
    half8_t h, l;
#pragma unroll
    for (int j = 0; j < 8; ++j) {
      const float v = T[ktl * 32 + quad * 8 + j][ntl * 16 + nr];
      const _Float16 hh = (_Float16)v;
      h[j] = hh;
      l[j] = (_Float16)((v - (float)hh) * 4096.f);
    }
    const size_t o = ((size_t)((n0 / 16 + ntl) * KT + (k0 / 32 + ktl)) * 64 + lane) * 8;
    *(half8_t*)(Wh + o) = h;
    *(half8_t*)(Wl + o) = l;
  }
}

// ---------------------------------------------------------------------------
// Merged prep: one launch does wconv(W0) + wconv(W1) + wconv(W2) + pack_wcat.
// Block-range dispatch: [0,1792) W0, [1792,2048) W1, [2048,2304) W2,
// [2304,2688) pack.
// ---------------------------------------------------------------------------
__global__ __launch_bounds__(256) void prep_kernel(
    const float* __restrict__ W0, _Float16* __restrict__ w0h, _Float16* __restrict__ w0l,
    const float* __restrict__ W1, _Float16* __restrict__ w1h, _Float16* __restrict__ w1l,
    const float* __restrict__ W2, _Float16* __restrict__ w2h, _Float16* __restrict__ w2l,
    const float* __restrict__ Wp, const float* __restrict__ Wv,
    float* __restrict__ Wc)
{
  int id = blockIdx.x;
  if (id < 1792) {                       // W0: 112 k-chunks x 16 n-chunks
    wconv_body(W0, w0h, w0l, KDIM0, KT0, id % 112, id / 112);
    return;
  }
  id -= 1792;
  if (id < 256) {                        // W1: 16 x 16
    wconv_body(W1, w1h, w1l, HDIM, KTH, id % 16, id / 16);
    return;
  }
  id -= 256;
  if (id < 256) {                        // W2: 16 x 16
    wconv_body(W2, w2h, w2l, HDIM, KTH, id % 16, id / 16);
    return;
  }
  id -= 256;                             // pack Wcat[1024][96]
  const int i = id * 256 + threadIdx.x;
  const int k = i / 96, c = i % 96;
  float v = 0.f;
  if (c < 94)       v = Wp[(size_t)k * 94 + c];
  else if (c == 94) v = Wv[k];
  Wc[i] = v;
}

// ---------------------------------------------------------------------------
// f16x3 split GEMM for layer 0, A read DIRECTLY from fp32 obs (adecomp fused).
// 2-phase double-buffered schedule: stage tile t+1 (W via global_load_lds,
// A via fp32 reg load -> in-register hi/lo split -> ds_write) BEFORE the MFMA
// phase on tile t; one __syncthreads per k-tile. A regs pipelined 2-deep.
// BM=128 (required: MFMA phase must cover staging latency — BM=64 regressed
// 2.4x, round-5; prefetch depth >1 under __syncthreads regressed, round-2).
// BK=32, LDS 2x32KB -> 2 blocks/CU.
// ---------------------------------------------------------------------------
__global__ __launch_bounds__(512, 4) void gemm_obs_kernel(
    const float* __restrict__ A,
    const _Float16* __restrict__ Wh, const _Float16* __restrict__ Wl,
    float* __restrict__ C, int ktsplit)
{
  __shared__ _Float16 As[2][2][8][512];   // [buf][plane][mt][frag]
  __shared__ _Float16 Ws[2][2][8][512];   // [buf][plane][nt][frag]
  // XCD-aware bijective swizzle: 512 blocks, 8 XCDs, chunk=64
  const int f  = blockIdx.x + 8 * (blockIdx.y + 32 * blockIdx.z);
  const int nf = (f & 7) * 64 + (f >> 3);
  const int bx = nf & 7, by = (nf >> 3) & 31, bz = nf >> 8;

  const int t    = threadIdx.x;
  const int lane = t & 63;
  const int w    = t >> 6;
  const int nt0  = bx * 8;
  const int mt0  = by * 8;
  const int ktb  = bz * ktsplit;
  const int nit  = ktsplit;            // k-tiles per block (BK=32), even
  const int l15  = lane & 15, quad = lane >> 4;
  const int wmi  = (w >> 2) * 4;
  const int wni  = (w & 3) * 2;

  // wave w stages A m-tile mt0+w (fp32) and W n-tile nt0+w (planes)
  const float* aRow = A + (size_t)((mt0 + w) * 16 + l15) * KDIM0 + quad * 8;
  const _Float16* wS0 = Wh + (size_t)(nt0 + w) * KT0 * 512 + lane * 8;
  const _Float16* wS1 = Wl + (size_t)(nt0 + w) * KT0 * 512 + lane * 8;

  struct AF8 { float v[8]; };
  auto loadA = [&](int kt) {
    AF8 r;
    const int kg = kt * 32 + quad * 8;
    const float* src = aRow + (size_t)kt * 32;
    if (kg + 8 <= KDIM0) {
#pragma unroll
      for (int c = 0; c < 4; ++c) {       // 8B-aligned only (KDIM0 odd stride)
        const float2 p = *(const float2*)(src + c * 2);
        r.v[c * 2] = p.x; r.v[c * 2 + 1] = p.y;
      }
    } else {
#pragma unroll
      for (int j = 0; j < 8; ++j)
        r.v[j] = (kg + j < KDIM0) ? src[j] : 0.f;
    }
    return r;
  };
  auto gw = [&](int kt, int buf) {
    GLOAD16(wS0 + (size_t)kt * 512, &Ws[buf][0][w][0]);
    GLOAD16(wS1 + (size_t)kt * 512, &Ws[buf][1][w][0]);
  };
  auto convst = [&](const AF8& a, int buf) {
    half8_t h, l;
#pragma unroll
    for (int j = 0; j < 8; ++j) {
      const float v = a.v[j];
      const _Float16 hh = (_Float16)v;
      h[j] = hh;
      l[j] = (_Float16)((v - (float)hh) * 4096.f);
    }
    *(half8_t*)&As[buf][0][w][lane * 8] = h;
    *(half8_t*)&As[buf][1][w][lane * 8] = l;
  };

  float4_t acc[4][2], accx[4][2];
#pragma unroll
  for (int i = 0; i < 4; ++i)
#pragma unroll
    for (int j = 0; j < 2; ++j) {
      acc[i][j]  = (float4_t){0.f, 0.f, 0.f, 0.f};
      accx[i][j] = (float4_t){0.f, 0.f, 0.f, 0.f};
    }

  auto mm = [&](int buf) {
    half8_t ah[4], al[4], wh[2], wl[2];
#pragma unroll
    for (int i = 0; i < 4; ++i) {
      ah[i] = *(const half8_t*)&As[buf][0][wmi + i][lane * 8];
      al[i] = *(const half8_t*)&As[buf][1][wmi + i][lane * 8];
    }
#pragma unroll
    for (int j = 0; j < 2; ++j) {
      wh[j] = *(const half8_t*)&Ws[buf][0][wni + j][lane * 8];
      wl[j] = *(const half8_t*)&Ws[buf][1][wni + j][lane * 8];
    }
#pragma unroll
    for (int i = 0; i < 4; ++i)
#pragma unroll
      for (int j = 0; j < 2; ++j) {
        acc[i][j]  = __builtin_amdgcn_mfma_f32_16x16x32_f16(ah[i], wh[j], acc[i][j], 0, 0, 0);
        accx[i][j] = __builtin_amdgcn_mfma_f32_16x16x32_f16(ah[i], wl[j], accx[i][j], 0, 0, 0);
        accx[i][j] = __builtin_amdgcn_mfma_f32_16x16x32_f16(al[i], wh[j], accx[i][j], 0, 0, 0);
      }
  };

  // prologue: tile0 staged into buf0; A regs for tiles 0,1 in flight
  AF8 vaE = loadA(ktb + 0);
  AF8 vaO = loadA(ktb + 1);
  gw(ktb + 0, 0);
  convst(vaE, 0);
  __syncthreads();

  for (int it = 0; it < nit; it += 2) {
    // iter it (even tile, buf0): stage tile it+1 -> buf1, prefetch A it+2.
    // A loads issued BEFORE the convert so the convert VALU covers them.
    gw(ktb + it + 1, 1);
    if (it + 2 < nit) vaE = loadA(ktb + it + 2);
    convst(vaO, 1);
    mm(0);
    __syncthreads();
    // iter it+1 (odd tile, buf1): stage tile it+2 -> buf0, prefetch A it+3
    if (it + 2 < nit) gw(ktb + it + 2, 0);
    if (it + 3 < nit) vaO = loadA(ktb + it + 3);
    if (it + 2 < nit) convst(vaE, 0);
    mm(1);
    __syncthreads();
  }

  float* Cb = C + (size_t)bz * ((size_t)BATCH * HDIM);
  const float sc = 1.0f / 4096.0f;
#pragma unroll
  for (int i = 0; i < 4; ++i) {
    const int row0 = (mt0 + wmi + i) * 16 + quad * 4;
#pragma unroll
    for (int j = 0; j < 2; ++j) {
      const int col = (nt0 + wni + j) * 16 + l15;
      float* cp = Cb + (size_t)row0 * HDIM + col;
#pragma unroll
      for (int r = 0; r < 4; ++r)
        cp[(size_t)r * HDIM] = acc[i][j][r] + accx[i][j][r] * sc;
    }
  }
}

// ---------------------------------------------------------------------------
// f16x3 split GEMM (layers 1/2), fragment-order planes, 2-phase double-
// buffered schedule: stage tile t+1 (4x global_load_lds) before MFMA on tile
// t; one __syncthreads per k-tile. BK=32, LDS 2x32KB. XCD-swizzled grid.
// ---------------------------------------------------------------------------
__global__ __launch_bounds__(512, 4) void gemm_frag2_kernel(
    const _Float16* __restrict__ Ah, const _Float16* __restrict__ Al,
    const _Float16* __restrict__ Wh, const _Float16* __restrict__ Wl,
    float* __restrict__ C, int KT, int ktsplit)
{
  __shared__ _Float16 As[2][2][8][512];   // [buf][plane][mt][frag]
  __shared__ _Float16 Ws[2][2][8][512];
  const int f  = blockIdx.x + 8 * (blockIdx.y + 32 * blockIdx.z);
  const int nf = (f & 7) * 64 + (f >> 3);
  const int bx = nf & 7, by = (nf >> 3) & 31, bz = nf >> 8;

  const int t    = threadIdx.x;
  const int lane = t & 63;
  const int w    = t >> 6;
  const int nt0  = bx * 8;
  const int mt0  = by * 8;
  const int ktb  = bz * ktsplit;
  const int nit  = ktsplit;            // k-tiles per block (BK=32), even
  const int l15  = lane & 15, quad = lane >> 4;
  const int wmi  = (w >> 2) * 4;
  const int wni  = (w & 3) * 2;

  const _Float16* aS0 = Ah + (size_t)(mt0 + w) * KT * 512 + lane * 8;
  const _Float16* aS1 = Al + (size_t)(mt0 + w) * KT * 512 + lane * 8;
  const _Float16* wS0 = Wh + (size_t)(nt0 + w) * KT * 512 + lane * 8;
  const _Float16* wS1 = Wl + (size_t)(nt0 + w) * KT * 512 + lane * 8;

  auto st = [&](int kt, int buf) {
    GLOAD16(aS0 + (size_t)kt * 512, &As[buf][0][w][0]);
    GLOAD16(aS1 + (size_t)kt * 512, &As[buf][1][w][0]);
    GLOAD16(wS0 + (size_t)kt * 512, &Ws[buf][0][w][0]);
    GLOAD16(wS1 + (size_t)kt * 512, &Ws[buf][1][w][0]);
  };

  float4_t acc[4][2], accx[4][2];
#pragma unroll
  for (int i = 0; i < 4; ++i)
#pragma unroll
    for (int j = 0; j < 2; ++j) {
      acc[i][j]  = (float4_t){0.f, 0.f, 0.f, 0.f};
      accx[i][j] = (float4_t){0.f, 0.f, 0.f, 0.f};
    }

  auto mm = [&](int buf) {
    half8_t ah[4], al[4], wh[2], wl[2];
#pragma unroll
    for (int i = 0; i < 4; ++i) {
      ah[i] = *(const half8_t*)&As[buf][0][wmi + i][lane * 8];
      al[i] = *(const half8_t*)&As[buf][1][wmi + i][lane * 8];
    }
#pragma unroll
    for (int j = 0; j < 2; ++j) {
      wh[j] = *(const half8_t*)&Ws[buf][0][wni + j][lane * 8];
      wl[j] = *(const half8_t*)&Ws[buf][1][wni + j][lane * 8];
    }
#pragma unroll
    for (int i = 0; i < 4; ++i)
#pragma unroll
      for (int j = 0; j < 2; ++j) {
        acc[i][j]  = __builtin_amdgcn_mfma_f32_16x16x32_f16(ah[i], wh[j], acc[i][j], 0, 0, 0);
        accx[i][j] = __builtin_amdgcn_mfma_f32_16x16x32_f16(ah[i], wl[j], accx[i][j], 0, 0, 0);
        accx[i][j] = __builtin_amdgcn_mfma_f32_16x16x32_f16(al[i], wh[j], accx[i][j], 0, 0, 0);
      }
  };

  st(ktb, 0);
  __syncthreads();
  for (int it = 0; it < nit; it += 2) {
    st(ktb + it + 1, 1);
    mm(0);
    __syncthreads();
    if (it + 2 < nit) st(ktb + it + 2, 0);
    mm(1);
    __syncthreads();
  }

  float* Cb = C + (size_t)bz * ((size_t)BATCH * HDIM);
  const float sc = 1.0f / 4096.0f;
#pragma unroll
  for (int i = 0; i < 4; ++i) {
    const int row0 = (mt0 + wmi + i) * 16 + quad * 4;
#pragma unroll
    for (int j = 0; j < 2; ++j) {
      const int col = (nt0 + wni + j) * 16 + l15;
      float* cp = Cb + (size_t)row0 * HDIM + col;
#pragma unroll
      for (int r = 0; r < 4; ++r)
        cp[(size_t)r * HDIM] = acc[i][j][r] + accx[i][j][r] * sc;
    }
  }
}

// ---------------------------------------------------------------------------
// sum halves + bias + LayerNorm + ReLU -> hi/lo f16 planes (fragment order).
// 1024 thr = 16 waves; wave w = row mt*16+w, wave-local reductions.
// ---------------------------------------------------------------------------
__global__ __launch_bounds__(1024) void ln_relu_f16_frag_kernel(
    const float* __restrict__ x0, const float* __restrict__ x1,
    const float* __restrict__ bias,
    const float* __restrict__ g, const float* __restrict__ be,
    _Float16* __restrict__ oh, _Float16* __restrict__ ol)
{
  const int t = threadIdx.x;
  const int w = t >> 6, lane = t & 63;
  const int mt = blockIdx.x;
  const float* xr0 = x0 + (size_t)(mt * 16 + w) * HDIM;
  const float* xr1 = x1 + (size_t)(mt * 16 + w) * HDIM;

  float4 v[4];
  float s = 0.f;
#pragma unroll
  for (int c = 0; c < 4; ++c) {
    const int k = c * 256 + lane * 4;
    const float4 a = *(const float4*)(xr0 + k);
    const float4 b = *(const float4*)(xr1 + k);
    const float4 bb = *(const float4*)(bias + k);
    v[c].x = a.x + b.x + bb.x; v[c].y = a.y + b.y + bb.y;
    v[c].z = a.z + b.z + bb.z; v[c].w = a.w + b.w + bb.w;
    s += (v[c].x + v[c].y) + (v[c].z + v[c].w);
  }
#pragma unroll
  for (int o = 32; o; o >>= 1) s += __shfl_xor(s, o, 64);
  const float mean = s * (1.0f / HDIM);

  float s2 = 0.f;
#pragma unroll
  for (int c = 0; c < 4; ++c) {
    v[c].x -= mean; v[c].y -= mean; v[c].z -= mean; v[c].w -= mean;
    s2 += (v[c].x * v[c].x + v[c].y * v[c].y) + (v[c].z * v[c].z + v[c].w * v[c].w);
  }
#pragma unroll
  for (int o = 32; o; o >>= 1) s2 += __shfl_xor(s2, o, 64);
  const float inv = 1.0f / sqrtf(s2 * (1.0f / HDIM) + 1e-5f);

  const int kt_b  = lane >> 3;
  const int quad  = (lane >> 1) & 3;
  const int jb    = (lane & 1) * 4;
#pragma unroll
  for (int c = 0; c < 4; ++c) {
    const int k = c * 256 + lane * 4;
    const float4 gg = *(const float4*)(g + k);
    const float4 ee = *(const float4*)(be + k);
    float r0 = fmaxf(fmaf(v[c].x * inv, gg.x, ee.x), 0.f);
    float r1 = fmaxf(fmaf(v[c].y * inv, gg.y, ee.y), 0.f);
    float r2 = fmaxf(fmaf(v[c].z * inv, gg.z, ee.z), 0.f);
    float r3 = fmaxf(fmaf(v[c].w * inv, gg.w, ee.w), 0.f);
    const _Float16 h0 = (_Float16)r0, h1 = (_Float16)r1, h2 = (_Float16)r2, h3 = (_Float16)r3;
    const half4_t hv = {h0, h1, h2, h3};
    const half4_t lv = {(_Float16)((r0 - (float)h0) * 4096.f),
                        (_Float16)((r1 - (float)h1) * 4096.f),
                        (_Float16)((r2 - (float)h2) * 4096.f),
                        (_Float16)((r3 - (float)h3) * 4096.f)};
    const int kt = c * 8 + kt_b;
    const size_t o = ((size_t)(mt * KTH + kt) * 64 + quad * 16 + w) * 8 + jb;
    *(half4_t*)(oh + o) = hv;
    *(half4_t*)(ol + o) = lv;
  }
}

// ---------------------------------------------------------------------------
// Fused: sum halves + bias + LN + ReLU  ->  head GEMM (+bp/bv)  ->  gumbel
// sampling. Block = 8 batch rows, 256 thr (4 waves).
// ---------------------------------------------------------------------------
__global__ __launch_bounds__(256) void head_fused_kernel(
    const float* __restrict__ x0, const float* __restrict__ x1,
    const float* __restrict__ b2, const float* __restrict__ g2,
    const float* __restrict__ be2,
    const float* __restrict__ Wc, const float* __restrict__ bp,
    const float* __restrict__ bv,
    const int* __restrict__ amask, const float* __restrict__ gum,
    float* __restrict__ out)
{
  __shared__ float Xs[8][1025];
  __shared__ float red[4][8][96];
  __shared__ float fl[8][96];
  __shared__ float rstat[16];
  const int t  = threadIdx.x;
  const int r0 = blockIdx.x * 8;
  const int wv = t >> 6, lane = t & 63;

  // stage: sum halves + pre-LN bias
#pragma unroll 4
  for (int i = 0; i < 32; ++i) {
    const int e = i * 256 + t;
    const int r = e >> 10, k = e & 1023;
    const size_t gi = (size_t)(r0 + r) * HDIM + k;
    Xs[r][k] = x0[gi] + x1[gi] + b2[k];
  }
  __syncthreads();

  // LN stats: wave wv handles rows wv and wv+4 (two-pass, matches reference)
#pragma unroll
  for (int rr = 0; rr < 2; ++rr) {
    const int row = wv + rr * 4;
    float s = 0.f;
#pragma unroll
    for (int ii = 0; ii < 16; ++ii) s += Xs[row][lane + 64 * ii];
#pragma unroll
    for (int o = 32; o; o >>= 1) s += __shfl_xor(s, o, 64);
    const float mean = s * (1.0f / HDIM);
    float s2 = 0.f;
#pragma unroll
    for (int ii = 0; ii < 16; ++ii) {
      const float d = Xs[row][lane + 64 * ii] - mean;
      s2 += d * d;
    }
#pragma unroll
    for (int o = 32; o; o >>= 1) s2 += __shfl_xor(s2, o, 64);
    if (lane == 0) {
      rstat[row] = mean;
      rstat[8 + row] = 1.0f / sqrtf(s2 * (1.0f / HDIM) + 1e-5f);
    }
  }
  __syncthreads();

  // normalize + relu in place
#pragma unroll 4
  for (int i = 0; i < 32; ++i) {
    const int e = i * 256 + t;
    const int r = e >> 10, k = e & 1023;
    Xs[r][k] = fmaxf(fmaf((Xs[r][k] - rstat[r]) * rstat[8 + r], g2[k], be2[k]), 0.f);
  }
  __syncthreads();

  // head GEMM: 16 tx (6 cols) x 4 ty (2 rows) x 4 kz
  const int tx = t & 15;
  const int ty = (t >> 4) & 3;
  const int kz = t >> 6;
  const int c0 = tx * 6;
  float acc[2][6] = {{0.f,0.f,0.f,0.f,0.f,0.f},{0.f,0.f,0.f,0.f,0.f,0.f}};
  const int kkend = kz * 256 + 256;
#pragma unroll 4
  for (int kk = kz * 256; kk < kkend; ++kk) {
    const float xa = Xs[ty * 2][kk];
    const float xb = Xs[ty * 2 + 1][kk];
    const float* wrow = Wc + (size_t)kk * 96 + c0;
    const float2 w01 = *(const float2*)(wrow);
    const float2 w23 = *(const float2*)(wrow + 2);
    const float2 w45 = *(const float2*)(wrow + 4);
    const float wvv[6] = {w01.x, w01.y, w23.x, w23.y, w45.x, w45.y};
#pragma unroll
    for (int j = 0; j < 6; ++j) {
      acc[0][j] = fmaf(xa, wvv[j], acc[0][j]);
      acc[1][j] = fmaf(xb, wvv[j], acc[1][j]);
    }
  }
#pragma unroll
  for (int r = 0; r < 2; ++r)
#pragma unroll
    for (int j = 0; j < 6; ++j) red[kz][ty * 2 + r][c0 + j] = acc[r][j];
  __syncthreads();

#pragma unroll
  for (int q = 0; q < 3; ++q) {
    const int e = t * 3 + q;
    const int row = e / 96, c = e % 96;
    const float sum = red[0][row][c] + red[1][row][c] + red[2][row][c] + red[3][row][c];
    if (c < 94) {
      const float vv = sum + bp[c];
      out[(size_t)(r0 + row) * NA2 + c] = vv;
      fl[row][c] = vv;
    } else if (c == 94) {
      out[VAL_OFF + r0 + row] = sum + bv[0];
    }
  }
  __syncthreads();

  // sampling: wave wv handles batch rows wv and wv+4
#pragma unroll
  for (int rr = 0; rr < 2; ++rr) {
    const int row = wv + rr * 4;
    const int b = r0 + row;
    const bool valid = lane < NACT;

    const float lg1 = valid ? fl[row][lane] : 0.f;
    const float lg2 = valid ? fl[row][NACT + lane] : 0.f;
    const int   mk1 = valid ? amask[(size_t)b * NA2 + lane] : 0;
    const int   mk2 = valid ? amask[(size_t)b * NA2 + NACT + lane] : 0;
    const float gu1 = valid ? gum[(size_t)b * NA2 + lane] : 0.f;
    const float gu2 = valid ? gum[(size_t)b * NA2 + NACT + lane] : 0.f;

    const float l1 = valid ? ((mk1 == 0) ? NEGC : lg1) : -INFINITY;
    float key = valid ? (l1 + gu1) : -INFINITY;
    int idx = lane;
#pragma unroll
    for (int o = 32; o; o >>= 1) {
      const float ok = __shfl_xor(key, o, 64);
      const int   oi = __shfl_xor(idx, o, 64);
      if (ok > key || (ok == key && oi < idx)) { key = ok; idx = oi; }
    }
    const int a1 = idx;

    float mx = l1;
#pragma unroll
    for (int o = 32; o; o >>= 1) mx = fmaxf(mx, __shfl_xor(mx, o, 64));
    float ex = valid ? expf(l1 - mx) : 0.f;
#pragma unroll
    for (int o = 32; o; o >>= 1) ex += __shfl_xor(ex, o, 64);
    const float logp1 = __shfl(l1, a1, 64) - (mx + logf(ex));

    int m2 = mk2;
    if (a1 >= 1 && a1 <= 6 && lane == a1) m2 = 0;
    if (a1 > 26 && a1 <= 46 && lane >= 27 && valid) m2 = 0;
    if (a1 == 0 && lane == 0) m2 = 0;
    int tot = m2;
#pragma unroll
    for (int o = 32; o; o >>= 1) tot += __shfl_xor(tot, o, 64);
    if (a1 == 0 && tot == 0 && lane == 0) m2 = 1;

    const float l2 = valid ? ((m2 == 0) ? NEGC : lg2) : -INFINITY;
    float key2 = valid ? (l2 + gu2) : -INFINITY;
    int idx2 = lane;
#pragma unroll
    for (int o = 32; o; o >>= 1) {
      const float ok = __shfl_xor(key2, o, 64);
      const int   oi = __shfl_xor(idx2, o, 64);
      if (ok > key2 || (ok == key2 && oi < idx2)) { key2 = ok; idx2 = oi; }
    }
    const int a2 = idx2;

    float mx2 = l2;
#pragma unroll
    for (int o = 32; o; o >>= 1) mx2 = fmaxf(mx2, __shfl_xor(mx2, o, 64));
    float ex2 = valid ? expf(l2 - mx2) : 0.f;
#pragma unroll
    for (int o = 32; o; o >>= 1) ex2 += __shfl_xor(ex2, o, 64);
    const float logp2 = __shfl(l2, a2, 64) - (mx2 + logf(ex2));

    if (lane == 0) {
      out[LP_OFF  + b * 2]     = logp1;
      out[LP_OFF  + b * 2 + 1] = logp2;
      out[ACT_OFF + b * 2]     = (float)a1;
      out[ACT_OFF + b * 2 + 1] = (float)a2;
    }
  }
}

// ---------------------------------------------------------------------------
extern "C" void kernel_launch(void* const* d_in, const int* in_sizes, int n_in,
                              void* d_out, int out_size, void* d_ws, size_t ws_size,
                              hipStream_t stream) {
  (void)in_sizes; (void)n_in; (void)out_size; (void)ws_size;
  const float* obs   = (const float*)d_in[0];
  const int*   amask = (const int*)  d_in[1];
  const float* gum   = (const float*)d_in[2];
  const float* W0    = (const float*)d_in[3];
  const float* b0    = (const float*)d_in[4];
  const float* g0    = (const float*)d_in[5];
  const float* be0   = (const float*)d_in[6];
  const float* W1    = (const float*)d_in[7];
  const float* b1    = (const float*)d_in[8];
  const float* g1    = (const float*)d_in[9];
  const float* be1   = (const float*)d_in[10];
  const float* W2    = (const float*)d_in[11];
  const float* b2    = (const float*)d_in[12];
  const float* g2    = (const float*)d_in[13];
  const float* be2   = (const float*)d_in[14];
  const float* Wp    = (const float*)d_in[15];
  const float* bp    = (const float*)d_in[16];
  const float* Wv    = (const float*)d_in[17];
  const float* bv    = (const float*)d_in[18];
  float* out = (float*)d_out;

  char* ws = (char*)d_ws;
  size_t off = 0;
  auto take = [&](size_t n) { char* p = ws + off; off += (n + 255) & ~(size_t)255; return p; };
  _Float16* w0h  = (_Float16*)take((size_t)HDIM * KP0 * 2);    // 14.7 MB
  _Float16* w0l  = (_Float16*)take((size_t)HDIM * KP0 * 2);    // 14.7 MB
  _Float16* w1h  = (_Float16*)take((size_t)HDIM * HDIM * 2);
  _Float16* w1l  = (_Float16*)take((size_t)HDIM * HDIM * 2);
  _Float16* w2h  = (_Float16*)take((size_t)HDIM * HDIM * 2);
  _Float16* w2l  = (_Float16*)take((size_t)HDIM * HDIM * 2);
  float*    xf   = (float*)   take((size_t)2 * BATCH * HDIM * 4); // 33.6 MB (2 halves)
  float*    wc   = (float*)   take((size_t)HDIM * 96 * 4);
  // activation f16 planes alias the (dead after GEMM0) W0 plane region
  _Float16* xph  = w0h;
  _Float16* xpl  = w0l;
  float* xf1 = xf + (size_t)BATCH * HDIM;

  // all weight conversions + head pack in ONE launch (block-range dispatch)
  prep_kernel<<<1792 + 256 + 256 + 384, 256, 0, stream>>>(
      W0, w0h, w0l, W1, w1h, w1l, W2, w2h, w2l, Wp, Wv, wc);

  // layer 0: A (obs fp32) decomposed in-kernel; 112 k-tiles per z-half
  gemm_obs_kernel<<<dim3(8, 32, 2), 512, 0, stream>>>(obs, w0h, w0l, xf, KT0 / 2);
  ln_relu_f16_frag_kernel<<<BATCH / 16, 1024, 0, stream>>>(xf, xf1, b0, g0, be0, xph, xpl);

  // layer 1: 16 k-tiles per z-half
  gemm_frag2_kernel<<<dim3(8, 32, 2), 512, 0, stream>>>(xph, xpl, w1h, w1l, xf, KTH, KTH / 2);
  ln_relu_f16_frag_kernel<<<BATCH / 16, 1024, 0, stream>>>(xf, xf1, b1, g1, be1, xph, xpl);

  // layer 2
  gemm_frag2_kernel<<<dim3(8, 32, 2), 512, 0, stream>>>(xph, xpl, w2h, w2l, xf, KTH, KTH / 2);

  // fused final-LN + heads + sampling
  head_fused_kernel<<<BATCH / 8, 256, 0, stream>>>(
      xf, xf1, b2, g2, be2, wc, bp, bv, amask, gum, out);
}